// Round 1
// baseline (733.115 us; speedup 1.0000x reference)
//
#include <hip/hip_runtime.h>
#include <hip/hip_bf16.h>

// R11: (a) CSR build re-parallelized: the 16-block binned count/scatter (each
// block re-scanned all 1.6M edges; ~6% CU utilization) replaced by full-grid
// global-atomic count + cursor scatter. Avg degree ~17 -> contention trivial.
// CSR neighbor order becomes nondeterministic; fp32 order noise is far below
// the bf16-grid compare tolerance. (b) Aggregation loops float4-ized: wave =
// 1 node, 4 edge-slots x 16 lanes x float4 (16B/lane), index prefetch breaks
// the csr->gather dependency chain. Same bytes, 1/4 the VMEM instructions.
// d_out is FLOAT32 (R10). Final layer NOT relu'd (R7). Matmuls unchanged.

__device__ __forceinline__ float leaky02(float x) { return x > 0.0f ? x : 0.2f * x; }

// ---------- CSR build (full-grid, global atomics) ----------
__global__ __launch_bounds__(256) void zero_kernel(int* __restrict__ p, int n) {
  int i = blockIdx.x * 256 + threadIdx.x;
  if (i < n) p[i] = 0;
}

__global__ __launch_bounds__(256) void count_kernel(
    const int* __restrict__ dst, int* __restrict__ cnt, int ne) {
  int e = blockIdx.x * 256 + threadIdx.x;
  if (e < ne) atomicAdd(&cnt[dst[e]], 1);
}

__global__ __launch_bounds__(1024) void scan1_kernel(int* __restrict__ cnt, int* __restrict__ bsums, int n) {
  __shared__ int s[1024];
  int gid = blockIdx.x * 1024 + threadIdx.x;
  int v = (gid < n) ? cnt[gid] : 0;
  s[threadIdx.x] = v;
  __syncthreads();
  for (int off = 1; off < 1024; off <<= 1) {
    int t = (threadIdx.x >= off) ? s[threadIdx.x - off] : 0;
    __syncthreads();
    s[threadIdx.x] += t;
    __syncthreads();
  }
  if (gid < n) cnt[gid] = s[threadIdx.x] - v;  // exclusive
  if (threadIdx.x == 1023) bsums[blockIdx.x] = s[1023];
}

__global__ __launch_bounds__(1024) void scan2_kernel(int* __restrict__ bsums, int nb) {
  __shared__ int s[1024];
  int v = (threadIdx.x < nb) ? bsums[threadIdx.x] : 0;
  s[threadIdx.x] = v;
  __syncthreads();
  for (int off = 1; off < 1024; off <<= 1) {
    int t = (threadIdx.x >= off) ? s[threadIdx.x - off] : 0;
    __syncthreads();
    s[threadIdx.x] += t;
    __syncthreads();
  }
  if (threadIdx.x < nb) bsums[threadIdx.x] = s[threadIdx.x] - v;
}

__global__ __launch_bounds__(1024) void scan3_kernel(
    const int* __restrict__ excl, const int* __restrict__ bsums,
    int* __restrict__ rowptr, int n, int ne) {
  int gid = blockIdx.x * 1024 + threadIdx.x;
  if (gid < n) rowptr[gid] = excl[gid] + bsums[blockIdx.x];
  if (gid == 0) rowptr[n] = ne;
}

// dinv + scatter-cursor init (cursor reuses the cnt buffer, dead after scan3)
__global__ __launch_bounds__(256) void prep_kernel(
    const int* __restrict__ rowptr, float* __restrict__ dinv, int* __restrict__ cur, int n) {
  int i = blockIdx.x * 256 + threadIdx.x;
  if (i < n) {
    int b = rowptr[i], e = rowptr[i + 1];
    dinv[i] = rsqrtf((float)(e - b + 1));  // +1 self-loop
    cur[i] = b;
  }
}

__global__ __launch_bounds__(256) void scatter_kernel(
    const int* __restrict__ src, const int* __restrict__ dst,
    int* __restrict__ cur, int* __restrict__ csr, int ne) {
  int e = blockIdx.x * 256 + threadIdx.x;
  if (e < ne) {
    int pos = atomicAdd(&cur[dst[e]], 1);
    csr[pos] = src[e];
  }
}

// ---------- dense matmul: C[n,64] = A[n,K] @ W[K,64], optional per-row dinv scale ----------
template<int K, bool SCALE>
__global__ __launch_bounds__(256) void matmul_kernel(
    const float* __restrict__ A, const float* __restrict__ W,
    const float* __restrict__ dinv, float* __restrict__ C, int n) {
  __shared__ float sW[K * 64];
  __shared__ float sA[16 * (K + 1)];
  const int tid = threadIdx.x;
  const int row0 = blockIdx.x * 16;
  for (int i = tid; i < K * 64; i += 256) sW[i] = W[i];
  for (int i = tid; i < 16 * K; i += 256) {
    int r = i / K, k = i - r * K;
    int row = row0 + r;
    sA[r * (K + 1) + k] = (row < n) ? A[(long)row * K + k] : 0.0f;
  }
  __syncthreads();
  const int r = tid >> 4;
  const int c4 = (tid & 15) * 4;
  float4 acc = make_float4(0.f, 0.f, 0.f, 0.f);
  const float* ap = &sA[r * (K + 1)];
#pragma unroll 16
  for (int k = 0; k < K; ++k) {
    float a = ap[k];
    float4 w = *reinterpret_cast<const float4*>(&sW[k * 64 + c4]);
    acc.x = fmaf(a, w.x, acc.x);
    acc.y = fmaf(a, w.y, acc.y);
    acc.z = fmaf(a, w.z, acc.z);
    acc.w = fmaf(a, w.w, acc.w);
  }
  int row = row0 + r;
  if (row < n) {
    float s = SCALE ? dinv[row] : 1.0f;
    float4 o = make_float4(acc.x * s, acc.y * s, acc.z * s, acc.w * s);
    *reinterpret_cast<float4*>(&C[(long)row * 64 + c4]) = o;
  }
}

// ---------- fused GCN aggregate + epilogue ----------
// wave = 1 node; lane = 4 edge-slots (g) x 16 channel-groups (float4 = c4..c4+3)
template<bool RELU>
__global__ __launch_bounds__(256) void gcn_layer_kernel(
    const int* __restrict__ rowptr, const int* __restrict__ csr,
    const float* __restrict__ hs, const float* __restrict__ dinv,
    const float* __restrict__ bias, float* __restrict__ out, int n) {
  int node = blockIdx.x * 4 + (threadIdx.x >> 6);
  if (node >= n) return;
  int lane = threadIdx.x & 63;
  int g = lane >> 4;           // edge slot 0..3
  int c4 = (lane & 15) * 4;    // channel block
  int beg = rowptr[node], end = rowptr[node + 1];
  float4 acc = make_float4(0.f, 0.f, 0.f, 0.f);
  int j = beg + g;
  int sn = (j < end) ? csr[j] : 0;           // index prefetch
  while (j < end) {
    int s = sn;
    j += 4;
    if (j < end) sn = csr[j];                // next index overlaps this gather
    float4 v = *reinterpret_cast<const float4*>(&hs[(long)s * 64 + c4]);
    acc.x += v.x; acc.y += v.y; acc.z += v.z; acc.w += v.w;
  }
  if (g == 0) {                              // self-loop (hs pre-scaled by dinv)
    float4 v = *reinterpret_cast<const float4*>(&hs[(long)node * 64 + c4]);
    acc.x += v.x; acc.y += v.y; acc.z += v.z; acc.w += v.w;
  }
  acc.x += __shfl_xor(acc.x, 16); acc.y += __shfl_xor(acc.y, 16);
  acc.z += __shfl_xor(acc.z, 16); acc.w += __shfl_xor(acc.w, 16);
  acc.x += __shfl_xor(acc.x, 32); acc.y += __shfl_xor(acc.y, 32);
  acc.z += __shfl_xor(acc.z, 32); acc.w += __shfl_xor(acc.w, 32);
  if (g == 0) {
    float s = dinv[node];
    float4 bb = *reinterpret_cast<const float4*>(&bias[c4]);
    float4 o = make_float4(fmaf(s, acc.x, bb.x), fmaf(s, acc.y, bb.y),
                           fmaf(s, acc.z, bb.z), fmaf(s, acc.w, bb.w));
    if (RELU) {
      o.x = fmaxf(o.x, 0.f); o.y = fmaxf(o.y, 0.f);
      o.z = fmaxf(o.z, 0.f); o.w = fmaxf(o.w, 0.f);
    }
    *reinterpret_cast<float4*>(&out[(long)node * 64 + c4]) = o;
  }
}

// ---------- GAT per-node attention logits ----------
__global__ void gat_alpha_kernel(
    const float* __restrict__ hg, const float* __restrict__ att_src, const float* __restrict__ att_dst,
    float* __restrict__ asrc, float* __restrict__ adst, int total) {
  int i = blockIdx.x * 256 + threadIdx.x;
  if (i >= total) return;
  int nrow = i >> 3, h = i & 7;
  const float* hp = &hg[(long)nrow * 64 + h * 8];
  float ss = 0.f, dd = 0.f;
#pragma unroll
  for (int c = 0; c < 8; ++c) {
    float v = hp[c];
    ss = fmaf(v, att_src[h * 8 + c], ss);
    dd = fmaf(v, att_dst[h * 8 + c], dd);
  }
  asrc[i] = ss;
  adst[i] = dd;
}

// ---------- fused GAT: in-wave softmax denom + weighted aggregation + relu ----------
__global__ __launch_bounds__(256) void gat_layer_kernel(
    const int* __restrict__ rowptr, const int* __restrict__ csr,
    const float* __restrict__ hg, const float* __restrict__ asrc,
    const float* __restrict__ adst, const float* __restrict__ bg,
    float* __restrict__ out, int n) {
  int node = blockIdx.x * 4 + (threadIdx.x >> 6);
  if (node >= n) return;
  int lane = threadIdx.x & 63;
  int beg = rowptr[node], end = rowptr[node + 1];
  // phase 1: softmax denominator per head; lane role h1 = lane&7, jj = lane>>3
  int h1 = lane & 7, jj = lane >> 3;
  float adn1 = adst[node * 8 + h1];
  float zp = 0.f;
  for (int j = beg + jj; j < end; j += 8) {
    int s = csr[j];
    zp += __expf(leaky02(asrc[s * 8 + h1] + adn1));
  }
  zp += __shfl_xor(zp, 8);
  zp += __shfl_xor(zp, 16);
  zp += __shfl_xor(zp, 32);
  zp += __expf(leaky02(asrc[node * 8 + h1] + adn1));  // self-loop term
  // phase 2: lane = 4 edge-slots (g) x 16 channel-groups; head h = c4>>3
  int g = lane >> 4;
  int c4 = (lane & 15) * 4;
  int h = c4 >> 3;
  float rz = 1.0f / __shfl(zp, h);    // lane h holds z[h] (its h1 == h)
  float adn2 = adst[node * 8 + h];
  float4 acc = make_float4(0.f, 0.f, 0.f, 0.f);
  int j = beg + g;
  int sn = (j < end) ? csr[j] : 0;
  while (j < end) {
    int s = sn;
    j += 4;
    if (j < end) sn = csr[j];
    float alpha = __expf(leaky02(asrc[s * 8 + h] + adn2)) * rz;
    float4 v = *reinterpret_cast<const float4*>(&hg[(long)s * 64 + c4]);
    acc.x = fmaf(alpha, v.x, acc.x);
    acc.y = fmaf(alpha, v.y, acc.y);
    acc.z = fmaf(alpha, v.z, acc.z);
    acc.w = fmaf(alpha, v.w, acc.w);
  }
  if (g == 0) {  // self-loop
    float aself = __expf(leaky02(asrc[node * 8 + h] + adn2)) * rz;
    float4 v = *reinterpret_cast<const float4*>(&hg[(long)node * 64 + c4]);
    acc.x = fmaf(aself, v.x, acc.x);
    acc.y = fmaf(aself, v.y, acc.y);
    acc.z = fmaf(aself, v.z, acc.z);
    acc.w = fmaf(aself, v.w, acc.w);
  }
  acc.x += __shfl_xor(acc.x, 16); acc.y += __shfl_xor(acc.y, 16);
  acc.z += __shfl_xor(acc.z, 16); acc.w += __shfl_xor(acc.w, 16);
  acc.x += __shfl_xor(acc.x, 32); acc.y += __shfl_xor(acc.y, 32);
  acc.z += __shfl_xor(acc.z, 32); acc.w += __shfl_xor(acc.w, 32);
  if (g == 0) {
    float4 bb = *reinterpret_cast<const float4*>(&bg[c4]);
    float4 o = make_float4(fmaxf(acc.x + bb.x, 0.f), fmaxf(acc.y + bb.y, 0.f),
                           fmaxf(acc.z + bb.z, 0.f), fmaxf(acc.w + bb.w, 0.f));
    *reinterpret_cast<float4*>(&out[(long)node * 64 + c4]) = o;
  }
}

extern "C" void kernel_launch(void* const* d_in, const int* in_sizes, int n_in,
                              void* d_out, int out_size, void* d_ws, size_t ws_size,
                              hipStream_t stream) {
  const float* x  = (const float*)d_in[0];
  const int* ei   = (const int*)d_in[1];
  const float* W0 = (const float*)d_in[2];
  const float* b0 = (const float*)d_in[3];
  const float* Wg = (const float*)d_in[4];
  const float* av = (const float*)d_in[5];
  const float* aw = (const float*)d_in[6];
  const float* bg = (const float*)d_in[7];
  const float* W2 = (const float*)d_in[8];
  const float* b2 = (const float*)d_in[9];
  const float* W3 = (const float*)d_in[10];
  const float* b3 = (const float*)d_in[11];

  const int N = in_sizes[0] / 128;
  const int E = in_sizes[1] / 2;
  const int* src = ei;
  const int* dst = ei + E;

  char* base = (char*)d_ws;
  size_t off = 0;
  auto alloc = [&](size_t bytes) {
    void* p = base + off;
    off = (off + bytes + 255) & ~(size_t)255;
    return p;
  };
  int*   cnt    = (int*)alloc((size_t)N * 4);   // doubles as scatter cursor
  int*   bsums  = (int*)alloc(1024 * 4);
  int*   rowptr = (int*)alloc((size_t)(N + 1) * 4);
  int*   csr    = (int*)alloc((size_t)E * 4);
  float* dinv   = (float*)alloc((size_t)N * 4);
  float* as_    = (float*)alloc((size_t)N * 8 * 4);
  float* ad_    = (float*)alloc((size_t)N * 8 * 4);
  float* bufA   = (float*)alloc((size_t)N * 64 * 4);
  float* bufB   = (float*)alloc((size_t)N * 64 * 4);
  (void)ws_size; (void)n_in; (void)out_size;

  const int gN    = (N + 255) / 256;
  const int gE    = (E + 255) / 256;
  const int gN8   = (N * 8 + 255) / 256;
  const int gMM   = (N + 15) / 16;
  const int gNode = (N + 3) / 4;
  const int nb    = (N + 1023) / 1024;

  // ---- CSR build (full-grid, two passes over edges) ----
  zero_kernel<<<gN, 256, 0, stream>>>(cnt, N);
  count_kernel<<<gE, 256, 0, stream>>>(dst, cnt, E);
  scan1_kernel<<<nb, 1024, 0, stream>>>(cnt, bsums, N);
  scan2_kernel<<<1, 1024, 0, stream>>>(bsums, nb);
  scan3_kernel<<<nb, 1024, 0, stream>>>(cnt, bsums, rowptr, N, E);
  prep_kernel<<<gN, 256, 0, stream>>>(rowptr, dinv, cnt, N);
  scatter_kernel<<<gE, 256, 0, stream>>>(src, dst, cnt, csr, E);

  // ---- GCN0 ----
  matmul_kernel<128, true><<<gMM, 256, 0, stream>>>(x, W0, dinv, bufA, N);
  gcn_layer_kernel<true><<<gNode, 256, 0, stream>>>(rowptr, csr, bufA, dinv, b0, bufB, N);

  // ---- GAT ----
  matmul_kernel<64, false><<<gMM, 256, 0, stream>>>(bufB, Wg, nullptr, bufA, N);
  gat_alpha_kernel<<<gN8, 256, 0, stream>>>(bufA, av, aw, as_, ad_, N * 8);
  gat_layer_kernel<<<gNode, 256, 0, stream>>>(rowptr, csr, bufA, as_, ad_, bg, bufB, N);

  // ---- GCN2 ----
  matmul_kernel<64, true><<<gMM, 256, 0, stream>>>(bufB, W2, dinv, bufA, N);
  gcn_layer_kernel<true><<<gNode, 256, 0, stream>>>(rowptr, csr, bufA, dinv, b2, bufB, N);

  // ---- GCN3: final layer, no relu, FLOAT32 out ----
  matmul_kernel<64, true><<<gMM, 256, 0, stream>>>(bufB, W3, dinv, bufA, N);
  gcn_layer_kernel<false><<<gNode, 256, 0, stream>>>(rowptr, csr, bufA, dinv, b3,
                                                     (float*)d_out, N);
}

// Round 2
// 605.733 us; speedup vs baseline: 1.2103x; 1.2103x over previous
//
#include <hip/hip_runtime.h>
#include <hip/hip_bf16.h>

// R12: CSR build rebuilt as bucketed two-phase partition to kill the 16x
// write amplification rocprof showed in scatter_kernel (105 MB WRITE_SIZE for
// a 6.4 MB csr; 124 us = top dispatch). Buckets are dst>>8 (256 nodes, ~4K
// edges). Phase 1: LDS-histogram + tiny scan + partition into (src,dst)
// records -- writes go to ~391 contiguous per-bucket streams, write-amp ~1x.
// Phase 2: one block per bucket derives rowptr from bucket base + LDS prefix
// scan (global count+scan kernels deleted) and scatters src into a ~16 KB
// L2-resident csr window with LDS cursors. Partition buffer aliases bufA.
// Aggregation + matmuls unchanged from R11. d_out FLOAT32, final layer no relu.

__device__ __forceinline__ float leaky02(float x) { return x > 0.0f ? x : 0.2f * x; }

#define NB_PART 64   // partition blocks (hist/scatter chunks)

// ---------- phase 1a: per-chunk bucket histogram ----------
__global__ __launch_bounds__(1024) void hist_kernel(
    const int* __restrict__ dst, int* __restrict__ hist, int ne, int nbkt) {
  __shared__ int h[512];
  const int tid = threadIdx.x;
  for (int i = tid; i < 512; i += 1024) h[i] = 0;
  __syncthreads();
  const int chunk = (ne + NB_PART - 1) / NB_PART;
  const int beg = blockIdx.x * chunk;
  const int end = min(beg + chunk, ne);
  for (int e = beg + tid; e < end; e += 1024) atomicAdd(&h[dst[e] >> 8], 1);
  __syncthreads();
  for (int i = tid; i < nbkt; i += 1024) hist[blockIdx.x * nbkt + i] = h[i];
}

// ---------- phase 1b: per-bucket cross-chunk prefix + bucket bases ----------
__global__ __launch_bounds__(512) void pscan_kernel(
    int* __restrict__ hist, int* __restrict__ bktBase, int nbkt, int ne) {
  __shared__ int tot[512];
  const int t = threadIdx.x;
  int run = 0;
  if (t < nbkt) {
    for (int b = 0; b < NB_PART; ++b) {
      int v = hist[b * nbkt + t];
      hist[b * nbkt + t] = run;  // per-chunk exclusive prefix within bucket
      run += v;
    }
  }
  tot[t] = (t < nbkt) ? run : 0;
  __syncthreads();
  for (int off = 1; off < 512; off <<= 1) {
    int u = (t >= off) ? tot[t - off] : 0;
    __syncthreads();
    tot[t] += u;
    __syncthreads();
  }
  if (t < nbkt) bktBase[t] = tot[t] - run;  // exclusive over buckets
  if (t == 0) bktBase[nbkt] = ne;
}

// ---------- phase 1c: partition (src,dst) into bucket-contiguous records ----------
__global__ __launch_bounds__(1024) void part_kernel(
    const int* __restrict__ src, const int* __restrict__ dst,
    const int* __restrict__ hist, const int* __restrict__ bktBase,
    int2* __restrict__ part, int ne, int nbkt) {
  __shared__ int cur[512];
  const int tid = threadIdx.x;
  for (int i = tid; i < nbkt; i += 1024)
    cur[i] = bktBase[i] + hist[blockIdx.x * nbkt + i];
  __syncthreads();
  const int chunk = (ne + NB_PART - 1) / NB_PART;
  const int beg = blockIdx.x * chunk;
  const int end = min(beg + chunk, ne);
  for (int e = beg + tid; e < end; e += 1024) {
    int d = dst[e];
    int s = src[e];
    int pos = atomicAdd(&cur[d >> 8], 1);
    part[pos] = make_int2(s, d);
  }
}

// ---------- phase 2: per-bucket rowptr + dinv + csr scatter (all LDS-local) ----------
__global__ __launch_bounds__(256) void build_kernel(
    const int2* __restrict__ part, const int* __restrict__ bktBase,
    int* __restrict__ rowptr, int* __restrict__ csr, float* __restrict__ dinv,
    int n, int ne) {
  __shared__ int cnt[256], sc[256], cur[256];
  const int b = blockIdx.x, tid = threadIdx.x;
  const int lo = b << 8;
  const int ebeg = bktBase[b], eend = bktBase[b + 1];
  cnt[tid] = 0;
  __syncthreads();
  for (int e = ebeg + tid; e < eend; e += 256) atomicAdd(&cnt[part[e].y - lo], 1);
  __syncthreads();
  sc[tid] = cnt[tid];
  __syncthreads();
  for (int off = 1; off < 256; off <<= 1) {
    int u = (tid >= off) ? sc[tid - off] : 0;
    __syncthreads();
    sc[tid] += u;
    __syncthreads();
  }
  const int excl = sc[tid] - cnt[tid];
  const int node = lo + tid;
  if (node < n) {
    rowptr[node] = ebeg + excl;
    dinv[node] = rsqrtf((float)(cnt[tid] + 1));  // +1 self-loop
  }
  cur[tid] = ebeg + excl;
  __syncthreads();
  for (int e = ebeg + tid; e < eend; e += 256) {
    int2 p = part[e];
    int pos = atomicAdd(&cur[p.y - lo], 1);  // LDS atomic
    csr[pos] = p.x;                          // write within ~16KB L2-hot window
  }
  if (b == 0 && tid == 0) rowptr[n] = ne;
}

// ---------- dense matmul: C[n,64] = A[n,K] @ W[K,64], optional per-row dinv scale ----------
template<int K, bool SCALE>
__global__ __launch_bounds__(256) void matmul_kernel(
    const float* __restrict__ A, const float* __restrict__ W,
    const float* __restrict__ dinv, float* __restrict__ C, int n) {
  __shared__ float sW[K * 64];
  __shared__ float sA[16 * (K + 1)];
  const int tid = threadIdx.x;
  const int row0 = blockIdx.x * 16;
  for (int i = tid; i < K * 64; i += 256) sW[i] = W[i];
  for (int i = tid; i < 16 * K; i += 256) {
    int r = i / K, k = i - r * K;
    int row = row0 + r;
    sA[r * (K + 1) + k] = (row < n) ? A[(long)row * K + k] : 0.0f;
  }
  __syncthreads();
  const int r = tid >> 4;
  const int c4 = (tid & 15) * 4;
  float4 acc = make_float4(0.f, 0.f, 0.f, 0.f);
  const float* ap = &sA[r * (K + 1)];
#pragma unroll 16
  for (int k = 0; k < K; ++k) {
    float a = ap[k];
    float4 w = *reinterpret_cast<const float4*>(&sW[k * 64 + c4]);
    acc.x = fmaf(a, w.x, acc.x);
    acc.y = fmaf(a, w.y, acc.y);
    acc.z = fmaf(a, w.z, acc.z);
    acc.w = fmaf(a, w.w, acc.w);
  }
  int row = row0 + r;
  if (row < n) {
    float s = SCALE ? dinv[row] : 1.0f;
    float4 o = make_float4(acc.x * s, acc.y * s, acc.z * s, acc.w * s);
    *reinterpret_cast<float4*>(&C[(long)row * 64 + c4]) = o;
  }
}

// ---------- fused GCN aggregate + epilogue ----------
// wave = 1 node; lane = 4 edge-slots (g) x 16 channel-groups (float4)
template<bool RELU>
__global__ __launch_bounds__(256) void gcn_layer_kernel(
    const int* __restrict__ rowptr, const int* __restrict__ csr,
    const float* __restrict__ hs, const float* __restrict__ dinv,
    const float* __restrict__ bias, float* __restrict__ out, int n) {
  int node = blockIdx.x * 4 + (threadIdx.x >> 6);
  if (node >= n) return;
  int lane = threadIdx.x & 63;
  int g = lane >> 4;           // edge slot 0..3
  int c4 = (lane & 15) * 4;    // channel block
  int beg = rowptr[node], end = rowptr[node + 1];
  float4 acc = make_float4(0.f, 0.f, 0.f, 0.f);
  int j = beg + g;
  int sn = (j < end) ? csr[j] : 0;           // index prefetch
  while (j < end) {
    int s = sn;
    j += 4;
    if (j < end) sn = csr[j];                // next index overlaps this gather
    float4 v = *reinterpret_cast<const float4*>(&hs[(long)s * 64 + c4]);
    acc.x += v.x; acc.y += v.y; acc.z += v.z; acc.w += v.w;
  }
  if (g == 0) {                              // self-loop (hs pre-scaled by dinv)
    float4 v = *reinterpret_cast<const float4*>(&hs[(long)node * 64 + c4]);
    acc.x += v.x; acc.y += v.y; acc.z += v.z; acc.w += v.w;
  }
  acc.x += __shfl_xor(acc.x, 16); acc.y += __shfl_xor(acc.y, 16);
  acc.z += __shfl_xor(acc.z, 16); acc.w += __shfl_xor(acc.w, 16);
  acc.x += __shfl_xor(acc.x, 32); acc.y += __shfl_xor(acc.y, 32);
  acc.z += __shfl_xor(acc.z, 32); acc.w += __shfl_xor(acc.w, 32);
  if (g == 0) {
    float s = dinv[node];
    float4 bb = *reinterpret_cast<const float4*>(&bias[c4]);
    float4 o = make_float4(fmaf(s, acc.x, bb.x), fmaf(s, acc.y, bb.y),
                           fmaf(s, acc.z, bb.z), fmaf(s, acc.w, bb.w));
    if (RELU) {
      o.x = fmaxf(o.x, 0.f); o.y = fmaxf(o.y, 0.f);
      o.z = fmaxf(o.z, 0.f); o.w = fmaxf(o.w, 0.f);
    }
    *reinterpret_cast<float4*>(&out[(long)node * 64 + c4]) = o;
  }
}

// ---------- GAT per-node attention logits ----------
__global__ void gat_alpha_kernel(
    const float* __restrict__ hg, const float* __restrict__ att_src, const float* __restrict__ att_dst,
    float* __restrict__ asrc, float* __restrict__ adst, int total) {
  int i = blockIdx.x * 256 + threadIdx.x;
  if (i >= total) return;
  int nrow = i >> 3, h = i & 7;
  const float* hp = &hg[(long)nrow * 64 + h * 8];
  float ss = 0.f, dd = 0.f;
#pragma unroll
  for (int c = 0; c < 8; ++c) {
    float v = hp[c];
    ss = fmaf(v, att_src[h * 8 + c], ss);
    dd = fmaf(v, att_dst[h * 8 + c], dd);
  }
  asrc[i] = ss;
  adst[i] = dd;
}

// ---------- fused GAT: in-wave softmax denom + weighted aggregation + relu ----------
__global__ __launch_bounds__(256) void gat_layer_kernel(
    const int* __restrict__ rowptr, const int* __restrict__ csr,
    const float* __restrict__ hg, const float* __restrict__ asrc,
    const float* __restrict__ adst, const float* __restrict__ bg,
    float* __restrict__ out, int n) {
  int node = blockIdx.x * 4 + (threadIdx.x >> 6);
  if (node >= n) return;
  int lane = threadIdx.x & 63;
  int beg = rowptr[node], end = rowptr[node + 1];
  // phase 1: softmax denominator per head; lane role h1 = lane&7, jj = lane>>3
  int h1 = lane & 7, jj = lane >> 3;
  float adn1 = adst[node * 8 + h1];
  float zp = 0.f;
  for (int j = beg + jj; j < end; j += 8) {
    int s = csr[j];
    zp += __expf(leaky02(asrc[s * 8 + h1] + adn1));
  }
  zp += __shfl_xor(zp, 8);
  zp += __shfl_xor(zp, 16);
  zp += __shfl_xor(zp, 32);
  zp += __expf(leaky02(asrc[node * 8 + h1] + adn1));  // self-loop term
  // phase 2: lane = 4 edge-slots (g) x 16 channel-groups; head h = c4>>3
  int g = lane >> 4;
  int c4 = (lane & 15) * 4;
  int h = c4 >> 3;
  float rz = 1.0f / __shfl(zp, h);    // lane h holds z[h] (its h1 == h)
  float adn2 = adst[node * 8 + h];
  float4 acc = make_float4(0.f, 0.f, 0.f, 0.f);
  int j = beg + g;
  int sn = (j < end) ? csr[j] : 0;
  while (j < end) {
    int s = sn;
    j += 4;
    if (j < end) sn = csr[j];
    float alpha = __expf(leaky02(asrc[s * 8 + h] + adn2)) * rz;
    float4 v = *reinterpret_cast<const float4*>(&hg[(long)s * 64 + c4]);
    acc.x = fmaf(alpha, v.x, acc.x);
    acc.y = fmaf(alpha, v.y, acc.y);
    acc.z = fmaf(alpha, v.z, acc.z);
    acc.w = fmaf(alpha, v.w, acc.w);
  }
  if (g == 0) {  // self-loop
    float aself = __expf(leaky02(asrc[node * 8 + h] + adn2)) * rz;
    float4 v = *reinterpret_cast<const float4*>(&hg[(long)node * 64 + c4]);
    acc.x = fmaf(aself, v.x, acc.x);
    acc.y = fmaf(aself, v.y, acc.y);
    acc.z = fmaf(aself, v.z, acc.z);
    acc.w = fmaf(aself, v.w, acc.w);
  }
  acc.x += __shfl_xor(acc.x, 16); acc.y += __shfl_xor(acc.y, 16);
  acc.z += __shfl_xor(acc.z, 16); acc.w += __shfl_xor(acc.w, 16);
  acc.x += __shfl_xor(acc.x, 32); acc.y += __shfl_xor(acc.y, 32);
  acc.z += __shfl_xor(acc.z, 32); acc.w += __shfl_xor(acc.w, 32);
  if (g == 0) {
    float4 bb = *reinterpret_cast<const float4*>(&bg[c4]);
    float4 o = make_float4(fmaxf(acc.x + bb.x, 0.f), fmaxf(acc.y + bb.y, 0.f),
                           fmaxf(acc.z + bb.z, 0.f), fmaxf(acc.w + bb.w, 0.f));
    *reinterpret_cast<float4*>(&out[(long)node * 64 + c4]) = o;
  }
}

extern "C" void kernel_launch(void* const* d_in, const int* in_sizes, int n_in,
                              void* d_out, int out_size, void* d_ws, size_t ws_size,
                              hipStream_t stream) {
  const float* x  = (const float*)d_in[0];
  const int* ei   = (const int*)d_in[1];
  const float* W0 = (const float*)d_in[2];
  const float* b0 = (const float*)d_in[3];
  const float* Wg = (const float*)d_in[4];
  const float* av = (const float*)d_in[5];
  const float* aw = (const float*)d_in[6];
  const float* bg = (const float*)d_in[7];
  const float* W2 = (const float*)d_in[8];
  const float* b2 = (const float*)d_in[9];
  const float* W3 = (const float*)d_in[10];
  const float* b3 = (const float*)d_in[11];

  const int N = in_sizes[0] / 128;
  const int E = in_sizes[1] / 2;
  const int* src = ei;
  const int* dst = ei + E;
  const int nbkt = (N + 255) >> 8;  // 391 for N=100000 (<=512 supported)

  char* base = (char*)d_ws;
  size_t off = 0;
  auto alloc = [&](size_t bytes) {
    void* p = base + off;
    off = (off + bytes + 255) & ~(size_t)255;
    return p;
  };
  int*   hist    = (int*)alloc((size_t)NB_PART * nbkt * 4);
  int*   bktBase = (int*)alloc((size_t)(nbkt + 1) * 4);
  int*   rowptr  = (int*)alloc((size_t)(N + 1) * 4);
  int*   csr     = (int*)alloc((size_t)E * 4);
  float* dinv    = (float*)alloc((size_t)N * 4);
  float* as_     = (float*)alloc((size_t)N * 8 * 4);
  float* ad_     = (float*)alloc((size_t)N * 8 * 4);
  float* bufA    = (float*)alloc((size_t)N * 64 * 4);
  float* bufB    = (float*)alloc((size_t)N * 64 * 4);
  int2*  part    = (int2*)bufA;  // 12.8MB alias; dead before first matmul writes bufA
  (void)ws_size; (void)n_in; (void)out_size;

  const int gN8   = (N * 8 + 255) / 256;
  const int gMM   = (N + 15) / 16;
  const int gNode = (N + 3) / 4;

  // ---- CSR build: bucketed partition, L2-local scatter ----
  hist_kernel<<<NB_PART, 1024, 0, stream>>>(dst, hist, E, nbkt);
  pscan_kernel<<<1, 512, 0, stream>>>(hist, bktBase, nbkt, E);
  part_kernel<<<NB_PART, 1024, 0, stream>>>(src, dst, hist, bktBase, part, E, nbkt);
  build_kernel<<<nbkt, 256, 0, stream>>>(part, bktBase, rowptr, csr, dinv, N, E);

  // ---- GCN0 ----
  matmul_kernel<128, true><<<gMM, 256, 0, stream>>>(x, W0, dinv, bufA, N);
  gcn_layer_kernel<true><<<gNode, 256, 0, stream>>>(rowptr, csr, bufA, dinv, b0, bufB, N);

  // ---- GAT ----
  matmul_kernel<64, false><<<gMM, 256, 0, stream>>>(bufB, Wg, nullptr, bufA, N);
  gat_alpha_kernel<<<gN8, 256, 0, stream>>>(bufA, av, aw, as_, ad_, N * 8);
  gat_layer_kernel<<<gNode, 256, 0, stream>>>(rowptr, csr, bufA, as_, ad_, bg, bufB, N);

  // ---- GCN2 ----
  matmul_kernel<64, true><<<gMM, 256, 0, stream>>>(bufB, W2, dinv, bufA, N);
  gcn_layer_kernel<true><<<gNode, 256, 0, stream>>>(rowptr, csr, bufA, dinv, b2, bufB, N);

  // ---- GCN3: final layer, no relu, FLOAT32 out ----
  matmul_kernel<64, true><<<gMM, 256, 0, stream>>>(bufB, W3, dinv, bufA, N);
  gcn_layer_kernel<false><<<gNode, 256, 0, stream>>>(rowptr, csr, bufA, dinv, b3,
                                                     (float*)d_out, N);
}

// Round 3
// 545.551 us; speedup vs baseline: 1.3438x; 1.1103x over previous
//
#include <hip/hip_runtime.h>
#include <hip/hip_bf16.h>

// R13: (a) gat_layer fused to single-pass softmax: accumulate unnormalized
// p*h and denominator z together, divide at end (no max-subtract needed --
// logits small, raw exp passed R12). Kills the second csr/asrc/exp pass.
// (b) matmul register-tiled: 64x64 block, 4x4 outputs/thread -> LDS traffic
// 2.5B/flop -> 1B/flop. CSR build + gcn_layer unchanged (control).
// d_out FLOAT32, final layer no relu.

__device__ __forceinline__ float leaky02(float x) { return x > 0.0f ? x : 0.2f * x; }

#define NB_PART 64   // partition blocks (hist/scatter chunks)

// ---------- phase 1a: per-chunk bucket histogram ----------
__global__ __launch_bounds__(1024) void hist_kernel(
    const int* __restrict__ dst, int* __restrict__ hist, int ne, int nbkt) {
  __shared__ int h[512];
  const int tid = threadIdx.x;
  for (int i = tid; i < 512; i += 1024) h[i] = 0;
  __syncthreads();
  const int chunk = (ne + NB_PART - 1) / NB_PART;
  const int beg = blockIdx.x * chunk;
  const int end = min(beg + chunk, ne);
  for (int e = beg + tid; e < end; e += 1024) atomicAdd(&h[dst[e] >> 8], 1);
  __syncthreads();
  for (int i = tid; i < nbkt; i += 1024) hist[blockIdx.x * nbkt + i] = h[i];
}

// ---------- phase 1b: per-bucket cross-chunk prefix + bucket bases ----------
__global__ __launch_bounds__(512) void pscan_kernel(
    int* __restrict__ hist, int* __restrict__ bktBase, int nbkt, int ne) {
  __shared__ int tot[512];
  const int t = threadIdx.x;
  int run = 0;
  if (t < nbkt) {
    for (int b = 0; b < NB_PART; ++b) {
      int v = hist[b * nbkt + t];
      hist[b * nbkt + t] = run;  // per-chunk exclusive prefix within bucket
      run += v;
    }
  }
  tot[t] = (t < nbkt) ? run : 0;
  __syncthreads();
  for (int off = 1; off < 512; off <<= 1) {
    int u = (t >= off) ? tot[t - off] : 0;
    __syncthreads();
    tot[t] += u;
    __syncthreads();
  }
  if (t < nbkt) bktBase[t] = tot[t] - run;  // exclusive over buckets
  if (t == 0) bktBase[nbkt] = ne;
}

// ---------- phase 1c: partition (src,dst) into bucket-contiguous records ----------
__global__ __launch_bounds__(1024) void part_kernel(
    const int* __restrict__ src, const int* __restrict__ dst,
    const int* __restrict__ hist, const int* __restrict__ bktBase,
    int2* __restrict__ part, int ne, int nbkt) {
  __shared__ int cur[512];
  const int tid = threadIdx.x;
  for (int i = tid; i < nbkt; i += 1024)
    cur[i] = bktBase[i] + hist[blockIdx.x * nbkt + i];
  __syncthreads();
  const int chunk = (ne + NB_PART - 1) / NB_PART;
  const int beg = blockIdx.x * chunk;
  const int end = min(beg + chunk, ne);
  for (int e = beg + tid; e < end; e += 1024) {
    int d = dst[e];
    int s = src[e];
    int pos = atomicAdd(&cur[d >> 8], 1);
    part[pos] = make_int2(s, d);
  }
}

// ---------- phase 2: per-bucket rowptr + dinv + csr scatter (all LDS-local) ----------
__global__ __launch_bounds__(256) void build_kernel(
    const int2* __restrict__ part, const int* __restrict__ bktBase,
    int* __restrict__ rowptr, int* __restrict__ csr, float* __restrict__ dinv,
    int n, int ne) {
  __shared__ int cnt[256], sc[256], cur[256];
  const int b = blockIdx.x, tid = threadIdx.x;
  const int lo = b << 8;
  const int ebeg = bktBase[b], eend = bktBase[b + 1];
  cnt[tid] = 0;
  __syncthreads();
  for (int e = ebeg + tid; e < eend; e += 256) atomicAdd(&cnt[part[e].y - lo], 1);
  __syncthreads();
  sc[tid] = cnt[tid];
  __syncthreads();
  for (int off = 1; off < 256; off <<= 1) {
    int u = (tid >= off) ? sc[tid - off] : 0;
    __syncthreads();
    sc[tid] += u;
    __syncthreads();
  }
  const int excl = sc[tid] - cnt[tid];
  const int node = lo + tid;
  if (node < n) {
    rowptr[node] = ebeg + excl;
    dinv[node] = rsqrtf((float)(cnt[tid] + 1));  // +1 self-loop
  }
  cur[tid] = ebeg + excl;
  __syncthreads();
  for (int e = ebeg + tid; e < eend; e += 256) {
    int2 p = part[e];
    int pos = atomicAdd(&cur[p.y - lo], 1);  // LDS atomic
    csr[pos] = p.x;                          // write within ~16KB L2-hot window
  }
  if (b == 0 && tid == 0) rowptr[n] = ne;
}

// ---------- dense matmul: C[n,64] = A[n,K] @ W[K,64], register-tiled ----------
// block = 64 rows x 64 cols, 256 threads, each 4x4 outputs. 1 LDS-byte/flop.
template<int K, bool SCALE>
__global__ __launch_bounds__(256) void matmul_kernel(
    const float* __restrict__ A, const float* __restrict__ W,
    const float* __restrict__ dinv, float* __restrict__ C, int n) {
  __shared__ float sW[K * 64];
  __shared__ float sA[64 * (K + 1)];
  const int tid = threadIdx.x;
  const int row0 = blockIdx.x * 64;
  // stage W (K*64 floats, contiguous float4s)
  for (int i = tid; i < K * 16; i += 256)
    reinterpret_cast<float4*>(sW)[i] = reinterpret_cast<const float4*>(W)[i];
  // stage A: 64 rows x K floats (padded stride K+1 -> scalar stores)
  const int f4r = K / 4;
  for (int i = tid; i < 64 * f4r; i += 256) {
    int r = i / f4r, f = i - r * f4r;
    int row = row0 + r;
    float4 v = (row < n)
        ? reinterpret_cast<const float4*>(&A[(long)row * K])[f]
        : make_float4(0.f, 0.f, 0.f, 0.f);
    float* p = &sA[r * (K + 1) + f * 4];
    p[0] = v.x; p[1] = v.y; p[2] = v.z; p[3] = v.w;
  }
  __syncthreads();
  const int tc = tid & 15, tr = tid >> 4;
  const int c0 = tc * 4, r0 = tr * 4;
  float4 acc0 = {0,0,0,0}, acc1 = {0,0,0,0}, acc2 = {0,0,0,0}, acc3 = {0,0,0,0};
  const float* a0 = &sA[(r0 + 0) * (K + 1)];
  const float* a1 = &sA[(r0 + 1) * (K + 1)];
  const float* a2 = &sA[(r0 + 2) * (K + 1)];
  const float* a3 = &sA[(r0 + 3) * (K + 1)];
#pragma unroll 8
  for (int k = 0; k < K; ++k) {
    float4 w = *reinterpret_cast<const float4*>(&sW[k * 64 + c0]);
    float x0 = a0[k], x1 = a1[k], x2 = a2[k], x3 = a3[k];
    acc0.x = fmaf(x0, w.x, acc0.x); acc0.y = fmaf(x0, w.y, acc0.y);
    acc0.z = fmaf(x0, w.z, acc0.z); acc0.w = fmaf(x0, w.w, acc0.w);
    acc1.x = fmaf(x1, w.x, acc1.x); acc1.y = fmaf(x1, w.y, acc1.y);
    acc1.z = fmaf(x1, w.z, acc1.z); acc1.w = fmaf(x1, w.w, acc1.w);
    acc2.x = fmaf(x2, w.x, acc2.x); acc2.y = fmaf(x2, w.y, acc2.y);
    acc2.z = fmaf(x2, w.z, acc2.z); acc2.w = fmaf(x2, w.w, acc2.w);
    acc3.x = fmaf(x3, w.x, acc3.x); acc3.y = fmaf(x3, w.y, acc3.y);
    acc3.z = fmaf(x3, w.z, acc3.z); acc3.w = fmaf(x3, w.w, acc3.w);
  }
  float4 accs[4] = {acc0, acc1, acc2, acc3};
#pragma unroll
  for (int i = 0; i < 4; ++i) {
    int row = row0 + r0 + i;
    if (row < n) {
      float s = SCALE ? dinv[row] : 1.0f;
      float4 o = make_float4(accs[i].x * s, accs[i].y * s,
                             accs[i].z * s, accs[i].w * s);
      *reinterpret_cast<float4*>(&C[(long)row * 64 + c0]) = o;
    }
  }
}

// ---------- fused GCN aggregate + epilogue ----------
// wave = 1 node; lane = 4 edge-slots (g) x 16 channel-groups (float4)
template<bool RELU>
__global__ __launch_bounds__(256) void gcn_layer_kernel(
    const int* __restrict__ rowptr, const int* __restrict__ csr,
    const float* __restrict__ hs, const float* __restrict__ dinv,
    const float* __restrict__ bias, float* __restrict__ out, int n) {
  int node = blockIdx.x * 4 + (threadIdx.x >> 6);
  if (node >= n) return;
  int lane = threadIdx.x & 63;
  int g = lane >> 4;           // edge slot 0..3
  int c4 = (lane & 15) * 4;    // channel block
  int beg = rowptr[node], end = rowptr[node + 1];
  float4 acc = make_float4(0.f, 0.f, 0.f, 0.f);
  int j = beg + g;
  int sn = (j < end) ? csr[j] : 0;           // index prefetch
  while (j < end) {
    int s = sn;
    j += 4;
    if (j < end) sn = csr[j];                // next index overlaps this gather
    float4 v = *reinterpret_cast<const float4*>(&hs[(long)s * 64 + c4]);
    acc.x += v.x; acc.y += v.y; acc.z += v.z; acc.w += v.w;
  }
  if (g == 0) {                              // self-loop (hs pre-scaled by dinv)
    float4 v = *reinterpret_cast<const float4*>(&hs[(long)node * 64 + c4]);
    acc.x += v.x; acc.y += v.y; acc.z += v.z; acc.w += v.w;
  }
  acc.x += __shfl_xor(acc.x, 16); acc.y += __shfl_xor(acc.y, 16);
  acc.z += __shfl_xor(acc.z, 16); acc.w += __shfl_xor(acc.w, 16);
  acc.x += __shfl_xor(acc.x, 32); acc.y += __shfl_xor(acc.y, 32);
  acc.z += __shfl_xor(acc.z, 32); acc.w += __shfl_xor(acc.w, 32);
  if (g == 0) {
    float s = dinv[node];
    float4 bb = *reinterpret_cast<const float4*>(&bias[c4]);
    float4 o = make_float4(fmaf(s, acc.x, bb.x), fmaf(s, acc.y, bb.y),
                           fmaf(s, acc.z, bb.z), fmaf(s, acc.w, bb.w));
    if (RELU) {
      o.x = fmaxf(o.x, 0.f); o.y = fmaxf(o.y, 0.f);
      o.z = fmaxf(o.z, 0.f); o.w = fmaxf(o.w, 0.f);
    }
    *reinterpret_cast<float4*>(&out[(long)node * 64 + c4]) = o;
  }
}

// ---------- GAT per-node attention logits ----------
__global__ void gat_alpha_kernel(
    const float* __restrict__ hg, const float* __restrict__ att_src, const float* __restrict__ att_dst,
    float* __restrict__ asrc, float* __restrict__ adst, int total) {
  int i = blockIdx.x * 256 + threadIdx.x;
  if (i >= total) return;
  int nrow = i >> 3, h = i & 7;
  const float* hp = &hg[(long)nrow * 64 + h * 8];
  float ss = 0.f, dd = 0.f;
#pragma unroll
  for (int c = 0; c < 8; ++c) {
    float v = hp[c];
    ss = fmaf(v, att_src[h * 8 + c], ss);
    dd = fmaf(v, att_dst[h * 8 + c], dd);
  }
  asrc[i] = ss;
  adst[i] = dd;
}

// ---------- fused GAT: SINGLE-PASS unnormalized accumulate + late divide ----------
// wave = 1 node; lane = 4 edge-slots (g) x 16 channel-groups; head h = c4>>3
__global__ __launch_bounds__(256) void gat_layer_kernel(
    const int* __restrict__ rowptr, const int* __restrict__ csr,
    const float* __restrict__ hg, const float* __restrict__ asrc,
    const float* __restrict__ adst, const float* __restrict__ bg,
    float* __restrict__ out, int n) {
  int node = blockIdx.x * 4 + (threadIdx.x >> 6);
  if (node >= n) return;
  int lane = threadIdx.x & 63;
  int g = lane >> 4;
  int c4 = (lane & 15) * 4;
  int h = c4 >> 3;
  int beg = rowptr[node], end = rowptr[node + 1];
  float adn = adst[node * 8 + h];
  float4 acc = make_float4(0.f, 0.f, 0.f, 0.f);
  float z = 0.f;
  int j = beg + g;
  int sn = (j < end) ? csr[j] : 0;
  while (j < end) {
    int s = sn;
    j += 4;
    if (j < end) sn = csr[j];
    float p = __expf(leaky02(asrc[s * 8 + h] + adn));
    float4 v = *reinterpret_cast<const float4*>(&hg[(long)s * 64 + c4]);
    z += p;
    acc.x = fmaf(p, v.x, acc.x);
    acc.y = fmaf(p, v.y, acc.y);
    acc.z = fmaf(p, v.z, acc.z);
    acc.w = fmaf(p, v.w, acc.w);
  }
  if (g == 0) {  // self-loop
    float p = __expf(leaky02(asrc[node * 8 + h] + adn));
    float4 v = *reinterpret_cast<const float4*>(&hg[(long)node * 64 + c4]);
    z += p;
    acc.x = fmaf(p, v.x, acc.x);
    acc.y = fmaf(p, v.y, acc.y);
    acc.z = fmaf(p, v.z, acc.z);
    acc.w = fmaf(p, v.w, acc.w);
  }
  // reduce acc and z over the 4 edge slots (lanes 16 apart share c4 and h)
  acc.x += __shfl_xor(acc.x, 16); acc.y += __shfl_xor(acc.y, 16);
  acc.z += __shfl_xor(acc.z, 16); acc.w += __shfl_xor(acc.w, 16);
  z += __shfl_xor(z, 16);
  acc.x += __shfl_xor(acc.x, 32); acc.y += __shfl_xor(acc.y, 32);
  acc.z += __shfl_xor(acc.z, 32); acc.w += __shfl_xor(acc.w, 32);
  z += __shfl_xor(z, 32);
  if (g == 0) {
    float rz = 1.0f / z;
    float4 bb = *reinterpret_cast<const float4*>(&bg[c4]);
    float4 o = make_float4(fmaxf(fmaf(acc.x, rz, bb.x), 0.f),
                           fmaxf(fmaf(acc.y, rz, bb.y), 0.f),
                           fmaxf(fmaf(acc.z, rz, bb.z), 0.f),
                           fmaxf(fmaf(acc.w, rz, bb.w), 0.f));
    *reinterpret_cast<float4*>(&out[(long)node * 64 + c4]) = o;
  }
}

extern "C" void kernel_launch(void* const* d_in, const int* in_sizes, int n_in,
                              void* d_out, int out_size, void* d_ws, size_t ws_size,
                              hipStream_t stream) {
  const float* x  = (const float*)d_in[0];
  const int* ei   = (const int*)d_in[1];
  const float* W0 = (const float*)d_in[2];
  const float* b0 = (const float*)d_in[3];
  const float* Wg = (const float*)d_in[4];
  const float* av = (const float*)d_in[5];
  const float* aw = (const float*)d_in[6];
  const float* bg = (const float*)d_in[7];
  const float* W2 = (const float*)d_in[8];
  const float* b2 = (const float*)d_in[9];
  const float* W3 = (const float*)d_in[10];
  const float* b3 = (const float*)d_in[11];

  const int N = in_sizes[0] / 128;
  const int E = in_sizes[1] / 2;
  const int* src = ei;
  const int* dst = ei + E;
  const int nbkt = (N + 255) >> 8;  // 391 for N=100000 (<=512 supported)

  char* base = (char*)d_ws;
  size_t off = 0;
  auto alloc = [&](size_t bytes) {
    void* p = base + off;
    off = (off + bytes + 255) & ~(size_t)255;
    return p;
  };
  int*   hist    = (int*)alloc((size_t)NB_PART * nbkt * 4);
  int*   bktBase = (int*)alloc((size_t)(nbkt + 1) * 4);
  int*   rowptr  = (int*)alloc((size_t)(N + 1) * 4);
  int*   csr     = (int*)alloc((size_t)E * 4);
  float* dinv    = (float*)alloc((size_t)N * 4);
  float* as_     = (float*)alloc((size_t)N * 8 * 4);
  float* ad_     = (float*)alloc((size_t)N * 8 * 4);
  float* bufA    = (float*)alloc((size_t)N * 64 * 4);
  float* bufB    = (float*)alloc((size_t)N * 64 * 4);
  int2*  part    = (int2*)bufA;  // 12.8MB alias; dead before first matmul writes bufA
  (void)ws_size; (void)n_in; (void)out_size;

  const int gN8   = (N * 8 + 255) / 256;
  const int gMM   = (N + 63) / 64;
  const int gNode = (N + 3) / 4;

  // ---- CSR build: bucketed partition, L2-local scatter ----
  hist_kernel<<<NB_PART, 1024, 0, stream>>>(dst, hist, E, nbkt);
  pscan_kernel<<<1, 512, 0, stream>>>(hist, bktBase, nbkt, E);
  part_kernel<<<NB_PART, 1024, 0, stream>>>(src, dst, hist, bktBase, part, E, nbkt);
  build_kernel<<<nbkt, 256, 0, stream>>>(part, bktBase, rowptr, csr, dinv, N, E);

  // ---- GCN0 ----
  matmul_kernel<128, true><<<gMM, 256, 0, stream>>>(x, W0, dinv, bufA, N);
  gcn_layer_kernel<true><<<gNode, 256, 0, stream>>>(rowptr, csr, bufA, dinv, b0, bufB, N);

  // ---- GAT ----
  matmul_kernel<64, false><<<gMM, 256, 0, stream>>>(bufB, Wg, nullptr, bufA, N);
  gat_alpha_kernel<<<gN8, 256, 0, stream>>>(bufA, av, aw, as_, ad_, N * 8);
  gat_layer_kernel<<<gNode, 256, 0, stream>>>(rowptr, csr, bufA, as_, ad_, bg, bufB, N);

  // ---- GCN2 ----
  matmul_kernel<64, true><<<gMM, 256, 0, stream>>>(bufB, W2, dinv, bufA, N);
  gcn_layer_kernel<true><<<gNode, 256, 0, stream>>>(rowptr, csr, bufA, dinv, b2, bufB, N);

  // ---- GCN3: final layer, no relu, FLOAT32 out ----
  matmul_kernel<64, true><<<gMM, 256, 0, stream>>>(bufB, W3, dinv, bufA, N);
  gcn_layer_kernel<false><<<gNode, 256, 0, stream>>>(rowptr, csr, bufA, dinv, b3,
                                                     (float*)d_out, N);
}

// Round 4
// 534.124 us; speedup vs baseline: 1.3726x; 1.0214x over previous
//
#include <hip/hip_runtime.h>
#include <hip/hip_bf16.h>

// R14: aggregation kernels restructured for memory-level parallelism.
// rocprof R13: gat_layer 80us, FETCH 264MB @3.3TB/s fill -- matches
// Little's-law latency bound (24 waves/CU x ~1.5 loads in flight x 64B /
// ~450ns), NOT an LLC bandwidth ceiling. Fix: wave = 8 edge-slots x 8 lanes
// x 2 float4 (2 independent row-gathers/lane in flight, 8 edges/chunk),
// coalesced csr index loads distributed via shfl, index prefetch 1 chunk
// ahead. Applied to gcn_layer + gat_layer. CSR build, matmuls, gat_alpha
// unchanged (control). d_out FLOAT32, final layer no relu.

__device__ __forceinline__ float leaky02(float x) { return x > 0.0f ? x : 0.2f * x; }

#define NB_PART 64   // partition blocks (hist/scatter chunks)

// ---------- phase 1a: per-chunk bucket histogram ----------
__global__ __launch_bounds__(1024) void hist_kernel(
    const int* __restrict__ dst, int* __restrict__ hist, int ne, int nbkt) {
  __shared__ int h[512];
  const int tid = threadIdx.x;
  for (int i = tid; i < 512; i += 1024) h[i] = 0;
  __syncthreads();
  const int chunk = (ne + NB_PART - 1) / NB_PART;
  const int beg = blockIdx.x * chunk;
  const int end = min(beg + chunk, ne);
  for (int e = beg + tid; e < end; e += 1024) atomicAdd(&h[dst[e] >> 8], 1);
  __syncthreads();
  for (int i = tid; i < nbkt; i += 1024) hist[blockIdx.x * nbkt + i] = h[i];
}

// ---------- phase 1b: per-bucket cross-chunk prefix + bucket bases ----------
__global__ __launch_bounds__(512) void pscan_kernel(
    int* __restrict__ hist, int* __restrict__ bktBase, int nbkt, int ne) {
  __shared__ int tot[512];
  const int t = threadIdx.x;
  int run = 0;
  if (t < nbkt) {
    for (int b = 0; b < NB_PART; ++b) {
      int v = hist[b * nbkt + t];
      hist[b * nbkt + t] = run;  // per-chunk exclusive prefix within bucket
      run += v;
    }
  }
  tot[t] = (t < nbkt) ? run : 0;
  __syncthreads();
  for (int off = 1; off < 512; off <<= 1) {
    int u = (t >= off) ? tot[t - off] : 0;
    __syncthreads();
    tot[t] += u;
    __syncthreads();
  }
  if (t < nbkt) bktBase[t] = tot[t] - run;  // exclusive over buckets
  if (t == 0) bktBase[nbkt] = ne;
}

// ---------- phase 1c: partition (src,dst) into bucket-contiguous records ----------
__global__ __launch_bounds__(1024) void part_kernel(
    const int* __restrict__ src, const int* __restrict__ dst,
    const int* __restrict__ hist, const int* __restrict__ bktBase,
    int2* __restrict__ part, int ne, int nbkt) {
  __shared__ int cur[512];
  const int tid = threadIdx.x;
  for (int i = tid; i < nbkt; i += 1024)
    cur[i] = bktBase[i] + hist[blockIdx.x * nbkt + i];
  __syncthreads();
  const int chunk = (ne + NB_PART - 1) / NB_PART;
  const int beg = blockIdx.x * chunk;
  const int end = min(beg + chunk, ne);
  for (int e = beg + tid; e < end; e += 1024) {
    int d = dst[e];
    int s = src[e];
    int pos = atomicAdd(&cur[d >> 8], 1);
    part[pos] = make_int2(s, d);
  }
}

// ---------- phase 2: per-bucket rowptr + dinv + csr scatter (all LDS-local) ----------
__global__ __launch_bounds__(256) void build_kernel(
    const int2* __restrict__ part, const int* __restrict__ bktBase,
    int* __restrict__ rowptr, int* __restrict__ csr, float* __restrict__ dinv,
    int n, int ne) {
  __shared__ int cnt[256], sc[256], cur[256];
  const int b = blockIdx.x, tid = threadIdx.x;
  const int lo = b << 8;
  const int ebeg = bktBase[b], eend = bktBase[b + 1];
  cnt[tid] = 0;
  __syncthreads();
  for (int e = ebeg + tid; e < eend; e += 256) atomicAdd(&cnt[part[e].y - lo], 1);
  __syncthreads();
  sc[tid] = cnt[tid];
  __syncthreads();
  for (int off = 1; off < 256; off <<= 1) {
    int u = (tid >= off) ? sc[tid - off] : 0;
    __syncthreads();
    sc[tid] += u;
    __syncthreads();
  }
  const int excl = sc[tid] - cnt[tid];
  const int node = lo + tid;
  if (node < n) {
    rowptr[node] = ebeg + excl;
    dinv[node] = rsqrtf((float)(cnt[tid] + 1));  // +1 self-loop
  }
  cur[tid] = ebeg + excl;
  __syncthreads();
  for (int e = ebeg + tid; e < eend; e += 256) {
    int2 p = part[e];
    int pos = atomicAdd(&cur[p.y - lo], 1);  // LDS atomic
    csr[pos] = p.x;                          // write within ~16KB L2-hot window
  }
  if (b == 0 && tid == 0) rowptr[n] = ne;
}

// ---------- dense matmul: C[n,64] = A[n,K] @ W[K,64], register-tiled ----------
// block = 64 rows x 64 cols, 256 threads, each 4x4 outputs. 1 LDS-byte/flop.
template<int K, bool SCALE>
__global__ __launch_bounds__(256) void matmul_kernel(
    const float* __restrict__ A, const float* __restrict__ W,
    const float* __restrict__ dinv, float* __restrict__ C, int n) {
  __shared__ float sW[K * 64];
  __shared__ float sA[64 * (K + 1)];
  const int tid = threadIdx.x;
  const int row0 = blockIdx.x * 64;
  for (int i = tid; i < K * 16; i += 256)
    reinterpret_cast<float4*>(sW)[i] = reinterpret_cast<const float4*>(W)[i];
  const int f4r = K / 4;
  for (int i = tid; i < 64 * f4r; i += 256) {
    int r = i / f4r, f = i - r * f4r;
    int row = row0 + r;
    float4 v = (row < n)
        ? reinterpret_cast<const float4*>(&A[(long)row * K])[f]
        : make_float4(0.f, 0.f, 0.f, 0.f);
    float* p = &sA[r * (K + 1) + f * 4];
    p[0] = v.x; p[1] = v.y; p[2] = v.z; p[3] = v.w;
  }
  __syncthreads();
  const int tc = tid & 15, tr = tid >> 4;
  const int c0 = tc * 4, r0 = tr * 4;
  float4 acc0 = {0,0,0,0}, acc1 = {0,0,0,0}, acc2 = {0,0,0,0}, acc3 = {0,0,0,0};
  const float* a0 = &sA[(r0 + 0) * (K + 1)];
  const float* a1 = &sA[(r0 + 1) * (K + 1)];
  const float* a2 = &sA[(r0 + 2) * (K + 1)];
  const float* a3 = &sA[(r0 + 3) * (K + 1)];
#pragma unroll 8
  for (int k = 0; k < K; ++k) {
    float4 w = *reinterpret_cast<const float4*>(&sW[k * 64 + c0]);
    float x0 = a0[k], x1 = a1[k], x2 = a2[k], x3 = a3[k];
    acc0.x = fmaf(x0, w.x, acc0.x); acc0.y = fmaf(x0, w.y, acc0.y);
    acc0.z = fmaf(x0, w.z, acc0.z); acc0.w = fmaf(x0, w.w, acc0.w);
    acc1.x = fmaf(x1, w.x, acc1.x); acc1.y = fmaf(x1, w.y, acc1.y);
    acc1.z = fmaf(x1, w.z, acc1.z); acc1.w = fmaf(x1, w.w, acc1.w);
    acc2.x = fmaf(x2, w.x, acc2.x); acc2.y = fmaf(x2, w.y, acc2.y);
    acc2.z = fmaf(x2, w.z, acc2.z); acc2.w = fmaf(x2, w.w, acc2.w);
    acc3.x = fmaf(x3, w.x, acc3.x); acc3.y = fmaf(x3, w.y, acc3.y);
    acc3.z = fmaf(x3, w.z, acc3.z); acc3.w = fmaf(x3, w.w, acc3.w);
  }
  float4 accs[4] = {acc0, acc1, acc2, acc3};
#pragma unroll
  for (int i = 0; i < 4; ++i) {
    int row = row0 + r0 + i;
    if (row < n) {
      float s = SCALE ? dinv[row] : 1.0f;
      float4 o = make_float4(accs[i].x * s, accs[i].y * s,
                             accs[i].z * s, accs[i].w * s);
      *reinterpret_cast<float4*>(&C[(long)row * 64 + c0]) = o;
    }
  }
}

// ---------- fused GCN aggregate + epilogue ----------
// wave = 1 node; lane = 8 edge-slots (slot=lane>>3) x 8 channel-lanes (li=lane&7).
// Each lane gathers 2 float4s (channels li*8 .. li*8+7) -> 8 edges + 16
// independent row-loads in flight per wave. Coalesced csr loads via shfl.
template<bool RELU>
__global__ __launch_bounds__(256) void gcn_layer_kernel(
    const int* __restrict__ rowptr, const int* __restrict__ csr,
    const float* __restrict__ hs, const float* __restrict__ dinv,
    const float* __restrict__ bias, float* __restrict__ out, int n) {
  int node = blockIdx.x * 4 + (threadIdx.x >> 6);
  if (node >= n) return;
  int lane = threadIdx.x & 63;
  int slot = lane >> 3;
  int li = lane & 7;
  int c0 = li * 8;
  int beg = rowptr[node], end = rowptr[node + 1];
  float4 accA = {0,0,0,0}, accB = {0,0,0,0};
  int j = beg;
  int idx = (j + li < end) ? csr[j + li] : 0;  // lanes 0..7 hold csr[j..j+7]
  while (j < end) {
    int s = __shfl(idx, slot);                 // slot g <- csr[j+g]
    bool valid = (j + slot) < end;
    int jn = j + 8;
    if (jn < end) idx = (jn + li < end) ? csr[jn + li] : 0;  // prefetch
    if (valid) {
      const float* hp = &hs[(long)s * 64 + c0];
      float4 va = *reinterpret_cast<const float4*>(hp);
      float4 vb = *reinterpret_cast<const float4*>(hp + 4);
      accA.x += va.x; accA.y += va.y; accA.z += va.z; accA.w += va.w;
      accB.x += vb.x; accB.y += vb.y; accB.z += vb.z; accB.w += vb.w;
    }
    j = jn;
  }
  if (slot == 0) {  // self-loop (hs pre-scaled by dinv)
    const float* hp = &hs[(long)node * 64 + c0];
    float4 va = *reinterpret_cast<const float4*>(hp);
    float4 vb = *reinterpret_cast<const float4*>(hp + 4);
    accA.x += va.x; accA.y += va.y; accA.z += va.z; accA.w += va.w;
    accB.x += vb.x; accB.y += vb.y; accB.z += vb.z; accB.w += vb.w;
  }
#pragma unroll
  for (int m = 8; m <= 32; m <<= 1) {
    accA.x += __shfl_xor(accA.x, m); accA.y += __shfl_xor(accA.y, m);
    accA.z += __shfl_xor(accA.z, m); accA.w += __shfl_xor(accA.w, m);
    accB.x += __shfl_xor(accB.x, m); accB.y += __shfl_xor(accB.y, m);
    accB.z += __shfl_xor(accB.z, m); accB.w += __shfl_xor(accB.w, m);
  }
  if (slot == 0) {
    float sdv = dinv[node];
    float4 bbA = *reinterpret_cast<const float4*>(&bias[c0]);
    float4 bbB = *reinterpret_cast<const float4*>(&bias[c0 + 4]);
    float4 oA = make_float4(fmaf(sdv, accA.x, bbA.x), fmaf(sdv, accA.y, bbA.y),
                            fmaf(sdv, accA.z, bbA.z), fmaf(sdv, accA.w, bbA.w));
    float4 oB = make_float4(fmaf(sdv, accB.x, bbB.x), fmaf(sdv, accB.y, bbB.y),
                            fmaf(sdv, accB.z, bbB.z), fmaf(sdv, accB.w, bbB.w));
    if (RELU) {
      oA.x = fmaxf(oA.x, 0.f); oA.y = fmaxf(oA.y, 0.f);
      oA.z = fmaxf(oA.z, 0.f); oA.w = fmaxf(oA.w, 0.f);
      oB.x = fmaxf(oB.x, 0.f); oB.y = fmaxf(oB.y, 0.f);
      oB.z = fmaxf(oB.z, 0.f); oB.w = fmaxf(oB.w, 0.f);
    }
    *reinterpret_cast<float4*>(&out[(long)node * 64 + c0]) = oA;
    *reinterpret_cast<float4*>(&out[(long)node * 64 + c0 + 4]) = oB;
  }
}

// ---------- GAT per-node attention logits ----------
__global__ void gat_alpha_kernel(
    const float* __restrict__ hg, const float* __restrict__ att_src, const float* __restrict__ att_dst,
    float* __restrict__ asrc, float* __restrict__ adst, int total) {
  int i = blockIdx.x * 256 + threadIdx.x;
  if (i >= total) return;
  int nrow = i >> 3, h = i & 7;
  const float* hp = &hg[(long)nrow * 64 + h * 8];
  float ss = 0.f, dd = 0.f;
#pragma unroll
  for (int c = 0; c < 8; ++c) {
    float v = hp[c];
    ss = fmaf(v, att_src[h * 8 + c], ss);
    dd = fmaf(v, att_dst[h * 8 + c], dd);
  }
  asrc[i] = ss;
  adst[i] = dd;
}

// ---------- fused GAT: single-pass unnormalized accumulate + late divide ----------
// wave = 1 node; 8 slots x 8 lanes; lane's channels = li*8..li*8+7, head h = li.
__global__ __launch_bounds__(256) void gat_layer_kernel(
    const int* __restrict__ rowptr, const int* __restrict__ csr,
    const float* __restrict__ hg, const float* __restrict__ asrc,
    const float* __restrict__ adst, const float* __restrict__ bg,
    float* __restrict__ out, int n) {
  int node = blockIdx.x * 4 + (threadIdx.x >> 6);
  if (node >= n) return;
  int lane = threadIdx.x & 63;
  int slot = lane >> 3;
  int li = lane & 7;
  int c0 = li * 8;
  int h = li;  // head for this lane's channels
  int beg = rowptr[node], end = rowptr[node + 1];
  float adn = adst[node * 8 + h];
  float4 accA = {0,0,0,0}, accB = {0,0,0,0};
  float z = 0.f;
  int j = beg;
  int idx = (j + li < end) ? csr[j + li] : 0;
  while (j < end) {
    int s = __shfl(idx, slot);
    bool valid = (j + slot) < end;
    int jn = j + 8;
    if (jn < end) idx = (jn + li < end) ? csr[jn + li] : 0;
    if (valid) {
      float p = __expf(leaky02(asrc[s * 8 + h] + adn));
      const float* hp = &hg[(long)s * 64 + c0];
      float4 va = *reinterpret_cast<const float4*>(hp);
      float4 vb = *reinterpret_cast<const float4*>(hp + 4);
      z += p;
      accA.x = fmaf(p, va.x, accA.x); accA.y = fmaf(p, va.y, accA.y);
      accA.z = fmaf(p, va.z, accA.z); accA.w = fmaf(p, va.w, accA.w);
      accB.x = fmaf(p, vb.x, accB.x); accB.y = fmaf(p, vb.y, accB.y);
      accB.z = fmaf(p, vb.z, accB.z); accB.w = fmaf(p, vb.w, accB.w);
    }
    j = jn;
  }
  if (slot == 0) {  // self-loop
    float p = __expf(leaky02(asrc[node * 8 + h] + adn));
    const float* hp = &hg[(long)node * 64 + c0];
    float4 va = *reinterpret_cast<const float4*>(hp);
    float4 vb = *reinterpret_cast<const float4*>(hp + 4);
    z += p;
    accA.x = fmaf(p, va.x, accA.x); accA.y = fmaf(p, va.y, accA.y);
    accA.z = fmaf(p, va.z, accA.z); accA.w = fmaf(p, va.w, accA.w);
    accB.x = fmaf(p, vb.x, accB.x); accB.y = fmaf(p, vb.y, accB.y);
    accB.z = fmaf(p, vb.z, accB.z); accB.w = fmaf(p, vb.w, accB.w);
  }
#pragma unroll
  for (int m = 8; m <= 32; m <<= 1) {
    accA.x += __shfl_xor(accA.x, m); accA.y += __shfl_xor(accA.y, m);
    accA.z += __shfl_xor(accA.z, m); accA.w += __shfl_xor(accA.w, m);
    accB.x += __shfl_xor(accB.x, m); accB.y += __shfl_xor(accB.y, m);
    accB.z += __shfl_xor(accB.z, m); accB.w += __shfl_xor(accB.w, m);
    z += __shfl_xor(z, m);
  }
  if (slot == 0) {
    float rz = 1.0f / z;
    float4 bbA = *reinterpret_cast<const float4*>(&bg[c0]);
    float4 bbB = *reinterpret_cast<const float4*>(&bg[c0 + 4]);
    float4 oA = make_float4(fmaxf(fmaf(accA.x, rz, bbA.x), 0.f),
                            fmaxf(fmaf(accA.y, rz, bbA.y), 0.f),
                            fmaxf(fmaf(accA.z, rz, bbA.z), 0.f),
                            fmaxf(fmaf(accA.w, rz, bbA.w), 0.f));
    float4 oB = make_float4(fmaxf(fmaf(accB.x, rz, bbB.x), 0.f),
                            fmaxf(fmaf(accB.y, rz, bbB.y), 0.f),
                            fmaxf(fmaf(accB.z, rz, bbB.z), 0.f),
                            fmaxf(fmaf(accB.w, rz, bbB.w), 0.f));
    *reinterpret_cast<float4*>(&out[(long)node * 64 + c0]) = oA;
    *reinterpret_cast<float4*>(&out[(long)node * 64 + c0 + 4]) = oB;
  }
}

extern "C" void kernel_launch(void* const* d_in, const int* in_sizes, int n_in,
                              void* d_out, int out_size, void* d_ws, size_t ws_size,
                              hipStream_t stream) {
  const float* x  = (const float*)d_in[0];
  const int* ei   = (const int*)d_in[1];
  const float* W0 = (const float*)d_in[2];
  const float* b0 = (const float*)d_in[3];
  const float* Wg = (const float*)d_in[4];
  const float* av = (const float*)d_in[5];
  const float* aw = (const float*)d_in[6];
  const float* bg = (const float*)d_in[7];
  const float* W2 = (const float*)d_in[8];
  const float* b2 = (const float*)d_in[9];
  const float* W3 = (const float*)d_in[10];
  const float* b3 = (const float*)d_in[11];

  const int N = in_sizes[0] / 128;
  const int E = in_sizes[1] / 2;
  const int* src = ei;
  const int* dst = ei + E;
  const int nbkt = (N + 255) >> 8;  // 391 for N=100000 (<=512 supported)

  char* base = (char*)d_ws;
  size_t off = 0;
  auto alloc = [&](size_t bytes) {
    void* p = base + off;
    off = (off + bytes + 255) & ~(size_t)255;
    return p;
  };
  int*   hist    = (int*)alloc((size_t)NB_PART * nbkt * 4);
  int*   bktBase = (int*)alloc((size_t)(nbkt + 1) * 4);
  int*   rowptr  = (int*)alloc((size_t)(N + 1) * 4);
  int*   csr     = (int*)alloc((size_t)E * 4);
  float* dinv    = (float*)alloc((size_t)N * 4);
  float* as_     = (float*)alloc((size_t)N * 8 * 4);
  float* ad_     = (float*)alloc((size_t)N * 8 * 4);
  float* bufA    = (float*)alloc((size_t)N * 64 * 4);
  float* bufB    = (float*)alloc((size_t)N * 64 * 4);
  int2*  part    = (int2*)bufA;  // 12.8MB alias; dead before first matmul writes bufA
  (void)ws_size; (void)n_in; (void)out_size;

  const int gN8   = (N * 8 + 255) / 256;
  const int gMM   = (N + 63) / 64;
  const int gNode = (N + 3) / 4;

  // ---- CSR build: bucketed partition, L2-local scatter ----
  hist_kernel<<<NB_PART, 1024, 0, stream>>>(dst, hist, E, nbkt);
  pscan_kernel<<<1, 512, 0, stream>>>(hist, bktBase, nbkt, E);
  part_kernel<<<NB_PART, 1024, 0, stream>>>(src, dst, hist, bktBase, part, E, nbkt);
  build_kernel<<<nbkt, 256, 0, stream>>>(part, bktBase, rowptr, csr, dinv, N, E);

  // ---- GCN0 ----
  matmul_kernel<128, true><<<gMM, 256, 0, stream>>>(x, W0, dinv, bufA, N);
  gcn_layer_kernel<true><<<gNode, 256, 0, stream>>>(rowptr, csr, bufA, dinv, b0, bufB, N);

  // ---- GAT ----
  matmul_kernel<64, false><<<gMM, 256, 0, stream>>>(bufB, Wg, nullptr, bufA, N);
  gat_alpha_kernel<<<gN8, 256, 0, stream>>>(bufA, av, aw, as_, ad_, N * 8);
  gat_layer_kernel<<<gNode, 256, 0, stream>>>(rowptr, csr, bufA, as_, ad_, bg, bufB, N);

  // ---- GCN2 ----
  matmul_kernel<64, true><<<gMM, 256, 0, stream>>>(bufB, W2, dinv, bufA, N);
  gcn_layer_kernel<true><<<gNode, 256, 0, stream>>>(rowptr, csr, bufA, dinv, b2, bufB, N);

  // ---- GCN3: final layer, no relu, FLOAT32 out ----
  matmul_kernel<64, true><<<gMM, 256, 0, stream>>>(bufB, W3, dinv, bufA, N);
  gcn_layer_kernel<false><<<gNode, 256, 0, stream>>>(rowptr, csr, bufA, dinv, b3,
                                                     (float*)d_out, N);
}